// Round 5
// baseline (2861.862 us; speedup 1.0000x reference)
//
#include <hip/hip_runtime.h>
#include <math.h>

#define PI_F 3.14159265358979323846f

// Persistent device scratch (rewritten fully on every launch).
__device__ float g_rwT[576 * 64];  // res_proj_w transposed: [p][c]
__device__ float g_dwT[576 * 6];   // data_proj_w transposed: [p][q]
__device__ float g_Ur[64 * 64];    // fixed-circuit unitary, real part [t][s]
__device__ float g_Ui[64 * 64];    // imag part [t][s]
__device__ float g_Zw[64 * 64];    // Zw[t][c] = sum_q out_proj_w[c,q]*sign_q(t)
__device__ float g_sang[48];       // style angles [b][q] (tanh*pi applied)
__device__ float g_cb[64];         // out_proj_b + res_proj_b

// ---------------------------------------------------------------------------
// Prep, 64-thread blocks.
//   bid 0      : Zw + combined bias
//   bid 1      : style angles
//   bid 2..65  : circuit column s = bid-2 (wave butterfly: lane t = state t,
//                gate pairs exchanged via __shfl_xor -> ~300-instr chain)
//   bid 66..641: weight transposes
__global__ __launch_bounds__(64) void k_prep(
        const float* __restrict__ style,
        const float* __restrict__ dw, const float* __restrict__ rw,
        const float* __restrict__ s2dw, const float* __restrict__ s2db,
        const float* __restrict__ qcnn, const float* __restrict__ meas,
        const float* __restrict__ outw, const float* __restrict__ outb,
        const float* __restrict__ resb) {
    int bid = blockIdx.x;
    int t = threadIdx.x;

    if (bid >= 66) {  // transposes
        int i = (bid - 66) * 64 + t;  // 0..36863
        if (i < 576 * 6) { int q = i / 576, p = i % 576; g_dwT[p * 6 + q] = dw[i]; }
        { int c = i / 576, p = i % 576; g_rwT[p * 64 + c] = rw[i]; }
        return;
    }
    if (bid == 0) {  // Zw row t + combined bias
        float zr[6];
#pragma unroll
        for (int q = 0; q < 6; ++q) zr[q] = ((t >> (5 - q)) & 1) ? -1.f : 1.f;
#pragma unroll 8
        for (int c = 0; c < 64; ++c) {
            float z = 0.f;
#pragma unroll
            for (int q = 0; q < 6; ++q) z += outw[c * 6 + q] * zr[q];
            g_Zw[t * 64 + c] = z;
        }
        g_cb[t] = outb[t] + resb[t];
        return;
    }
    if (bid == 1) {  // style angles [b][q]
        if (t < 48) {
            int bb = t / 6, q = t % 6;
            float a = s2db[q];
#pragma unroll 8
            for (int j = 0; j < 128; ++j) a += style[bb * 128 + j] * s2dw[q * 128 + j];
            g_sang[t] = tanhf(a) * PI_F;
        }
        return;
    }

    // Circuit column s: lane t holds amplitude of basis state t (wire q = bit 5-q).
    int s = bid - 2;
    float ar = (t == s) ? 1.f : 0.f;
    float ai = 0.f;

#pragma unroll
    for (int l = 0; l < 2; ++l) {
#pragma unroll
        for (int wq = 0; wq < 6; ++wq) {
            int mask = 1 << (5 - wq);
            bool hi = (t & mask) != 0;
            // RY(theta): a0' = c a0 - s a1 ; a1' = s a0 + c a1
            float th = qcnn[((l * 6 + wq) * 2 + 0) * 3];
            float sg, cg; sincosf(0.5f * th, &sg, &cg);
            float pr = __shfl_xor(ar, mask);
            float pi2 = __shfl_xor(ai, mask);
            ar = hi ? (sg * pr + cg * ar) : (cg * ar - sg * pr);
            ai = hi ? (sg * pi2 + cg * ai) : (cg * ai - sg * pi2);
            // RZ(phi): diag(e^{-i phi/2}, e^{+i phi/2})
            float ph = qcnn[((l * 6 + wq) * 2 + 1) * 3];
            float sz, cz; sincosf(0.5f * ph, &sz, &cz);
            float szz = hi ? sz : -sz;
            float nr = cz * ar - szz * ai;
            float ni = cz * ai + szz * ar;
            ar = nr; ai = ni;
        }
#pragma unroll
        for (int wq = 0; wq < 6; ++wq) {  // ring CNOTs
            int cm = 1 << (5 - wq);
            int tm = 1 << (5 - ((wq + 1) % 6));
            float pr = __shfl_xor(ar, tm);
            float pi2 = __shfl_xor(ai, tm);
            if (t & cm) { ar = pr; ai = pi2; }
        }
    }
#pragma unroll
    for (int wq = 0; wq < 6; ++wq) {  // U3 measurement basis
        int mask = 1 << (5 - wq);
        bool hi = (t & mask) != 0;
        float th = meas[wq * 3 + 0], ph = meas[wq * 3 + 1], lm = meas[wq * 3 + 2];
        float st2, ct; sincosf(0.5f * th, &st2, &ct);
        float sl, cl;  sincosf(lm, &sl, &cl);
        float sp, cp;  sincosf(ph, &sp, &cp);
        float spl, cpl; sincosf(ph + lm, &spl, &cpl);
        float u01r = -cl * st2, u01i = -sl * st2;
        float u10r =  cp * st2, u10i =  sp * st2;
        float u11r =  cpl * ct, u11i =  spl * ct;
        float pr = __shfl_xor(ar, mask);
        float pi2 = __shfl_xor(ai, mask);
        float nr, ni;
        if (hi) {  // a1' = u10 a0 + u11 a1   (partner holds a0)
            nr = u10r * pr - u10i * pi2 + u11r * ar - u11i * ai;
            ni = u10r * pi2 + u10i * pr + u11r * ai + u11i * ar;
        } else {   // a0' = ct a0 + u01 a1    (partner holds a1)
            nr = ct * ar + u01r * pr - u01i * pi2;
            ni = ct * ai + u01r * pi2 + u01i * pr;
        }
        ar = nr; ai = ni;
    }
    g_Ur[t * 64 + s] = ar;
    g_Ui[t * 64 + s] = ai;
}

// ---------------------------------------------------------------------------
// Main: 64 pixels per block (one h-row: b,h block-uniform, lane == w).
// 8 slices (waves); slice owns OUTPUT channels/states [8*slice, 8*slice+8).
// x staged through LDS in 16-channel chunks (3 rows x 66 cols, halo zeroed):
// 648 global loads/thread -> 24 coalesced global + 576 conflict-free ds_read.
__global__ __launch_bounds__(512, 4) void k_main(const float* __restrict__ x,
                                                 const float* __restrict__ dpb,
                                                 float* __restrict__ out) {
    __shared__ float xs[16 * 3 * 66];    // [ci][row][w+1], 12672 B
    __shared__ float lds_ang[6 * 512];   // [q][thread]
    __shared__ float lds_psi[64 * 65];   // [pixel][s]
    __shared__ float lds_prob[64 * 65];  // [pixel][t]

    int lane  = threadIdx.x & 63;
    int slice = __builtin_amdgcn_readfirstlane(threadIdx.x >> 6);  // 0..7
    int c0 = slice * 8;

    int p = blockIdx.x * 64 + lane;      // b,h uniform across block; lane = w
    int b = p >> 12;
    int h = (p >> 6) & 63;
    const float* xb = x + (b << 18);

    // zero the 96 halo slots once (never overwritten by stagers)
    if (threadIdx.x < 96) {
        int ci = threadIdx.x / 6, rem = threadIdx.x % 6;
        xs[(ci * 3 + (rem >> 1)) * 66 + (rem & 1) * 65] = 0.f;
    }

    float acc[8];
#pragma unroll
    for (int k = 0; k < 8; ++k) acc[k] = 0.f;
    float ang[6] = {0.f, 0.f, 0.f, 0.f, 0.f, 0.f};

    for (int chunk = 0; chunk < 4; ++chunk) {
        int cbase = chunk * 16;
        __syncthreads();  // xs free (also covers halo init on first pass)
        // stage 16 channels x 3 rows x 64 w = 3072 floats, 6 per thread
#pragma unroll
        for (int k = 0; k < 6; ++k) {
            int idx = threadIdx.x + k * 512;
            int ci  = idx / 192;
            int rem = idx - ci * 192;
            int row = rem >> 6;
            int ww  = rem & 63;
            int hh  = h + row - 1;
            float v = 0.f;
            if ((unsigned)hh < 64u) v = xb[((cbase + ci) << 12) + (hh << 6) + ww];
            xs[(ci * 3 + row) * 66 + ww + 1] = v;
        }
        __syncthreads();
        // conv from LDS
#pragma unroll 8
        for (int ci = 0; ci < 16; ++ci) {
            int c = cbase + ci;
#pragma unroll
            for (int row = 0; row < 3; ++row) {
                const float* xr = &xs[(ci * 3 + row) * 66 + lane];
                float vl = xr[0], vm = xr[1], vr = xr[2];
                const float* wp = g_rwT + ((c * 9 + row * 3) << 6) + c0;
                const float4 a0 = *(const float4*)(wp);
                const float4 a1 = *(const float4*)(wp + 4);
                const float4 b0 = *(const float4*)(wp + 64);
                const float4 b1 = *(const float4*)(wp + 68);
                const float4 d0 = *(const float4*)(wp + 128);
                const float4 d1 = *(const float4*)(wp + 132);
                acc[0] += vl * a0.x + vm * b0.x + vr * d0.x;
                acc[1] += vl * a0.y + vm * b0.y + vr * d0.y;
                acc[2] += vl * a0.z + vm * b0.z + vr * d0.z;
                acc[3] += vl * a0.w + vm * b0.w + vr * d0.w;
                acc[4] += vl * a1.x + vm * b1.x + vr * d1.x;
                acc[5] += vl * a1.y + vm * b1.y + vr * d1.y;
                acc[6] += vl * a1.z + vm * b1.z + vr * d1.z;
                acc[7] += vl * a1.w + vm * b1.w + vr * d1.w;
                if ((c >> 3) == slice) {  // this slice's angle channels
                    const float* dp = g_dwT + (c * 9 + row * 3) * 6;
#pragma unroll
                    for (int q = 0; q < 6; ++q)
                        ang[q] += vl * dp[q] + vm * dp[6 + q] + vr * dp[12 + q];
                }
            }
        }
    }
#pragma unroll
    for (int q = 0; q < 6; ++q) lds_ang[q * 512 + threadIdx.x] = ang[q];

    // ---- reduce angles across the 8 slices, finish theta, sincos
    __syncthreads();
    float sc[6], cc[6];
#pragma unroll
    for (int q = 0; q < 6; ++q) {
        const float* a = lds_ang + q * 512 + lane;
        float t = 0.f;
#pragma unroll
        for (int s2 = 0; s2 < 8; ++s2) t += a[s2 * 64];
        float theta = tanhf(t + dpb[q]) * PI_F + g_sang[b * 6 + q];
        sincosf(0.5f * theta, &sc[q], &cc[q]);
    }

    // ---- cooperative psi: this thread builds states s = c0..c0+7
#pragma unroll
    for (int ti = 0; ti < 8; ++ti) {
        int s = c0 + ti;
        float v = ((s >> 5) & 1) ? sc[0] : cc[0];
        v *= ((s >> 4) & 1) ? sc[1] : cc[1];
        v *= ((s >> 3) & 1) ? sc[2] : cc[2];
        v *= ((s >> 2) & 1) ? sc[3] : cc[3];
        v *= ((s >> 1) & 1) ? sc[4] : cc[4];
        v *= (s & 1)        ? sc[5] : cc[5];
        lds_psi[lane * 65 + s] = v;
    }
    __syncthreads();

    // ---- probs for this slice's 8 states: stream psi from LDS in blocks of 8
    float yr[8], yi[8];
#pragma unroll
    for (int t = 0; t < 8; ++t) { yr[t] = 0.f; yi[t] = 0.f; }
#pragma unroll
    for (int s0 = 0; s0 < 8; ++s0) {
        float ps[8];
#pragma unroll
        for (int k = 0; k < 8; ++k) ps[k] = lds_psi[lane * 65 + s0 * 8 + k];
#pragma unroll
        for (int t = 0; t < 8; ++t) {
            const float4 u0 = *(const float4*)(g_Ur + ((c0 + t) << 6) + s0 * 8);
            const float4 u1 = *(const float4*)(g_Ur + ((c0 + t) << 6) + s0 * 8 + 4);
            const float4 v0 = *(const float4*)(g_Ui + ((c0 + t) << 6) + s0 * 8);
            const float4 v1 = *(const float4*)(g_Ui + ((c0 + t) << 6) + s0 * 8 + 4);
            yr[t] += u0.x * ps[0] + u0.y * ps[1] + u0.z * ps[2] + u0.w * ps[3]
                   + u1.x * ps[4] + u1.y * ps[5] + u1.z * ps[6] + u1.w * ps[7];
            yi[t] += v0.x * ps[0] + v0.y * ps[1] + v0.z * ps[2] + v0.w * ps[3]
                   + v1.x * ps[4] + v1.y * ps[5] + v1.z * ps[6] + v1.w * ps[7];
        }
    }
#pragma unroll
    for (int t = 0; t < 8; ++t)
        lds_prob[lane * 65 + c0 + t] = yr[t] * yr[t] + yi[t] * yi[t];
    __syncthreads();

    // ---- fold probs through Zw into this slice's 8 output channels
#pragma unroll 8
    for (int t = 0; t < 64; ++t) {
        float pr = lds_prob[lane * 65 + t];
        const float4 z0 = *(const float4*)(g_Zw + (t << 6) + c0);
        const float4 z1 = *(const float4*)(g_Zw + (t << 6) + c0 + 4);
        acc[0] += pr * z0.x; acc[1] += pr * z0.y;
        acc[2] += pr * z0.z; acc[3] += pr * z0.w;
        acc[4] += pr * z1.x; acc[5] += pr * z1.y;
        acc[6] += pr * z1.z; acc[7] += pr * z1.w;
    }

    // ---- coalesced store: out[b][c][h][w]
    int ob = (b << 18) + (h << 6) + lane;
#pragma unroll
    for (int k = 0; k < 8; ++k) {
        out[ob + ((c0 + k) << 12)] = acc[k] + g_cb[c0 + k];
    }
}

// ---------------------------------------------------------------------------
extern "C" void kernel_launch(void* const* d_in, const int* in_sizes, int n_in,
                              void* d_out, int out_size, void* d_ws, size_t ws_size,
                              hipStream_t stream) {
    const float* x     = (const float*)d_in[0];
    const float* style = (const float*)d_in[1];
    const float* dw    = (const float*)d_in[2];
    const float* dpb   = (const float*)d_in[3];
    const float* s2dw  = (const float*)d_in[4];
    const float* s2db  = (const float*)d_in[5];
    const float* qcnn  = (const float*)d_in[6];
    const float* meas  = (const float*)d_in[7];
    const float* outw  = (const float*)d_in[8];
    const float* outb  = (const float*)d_in[9];
    const float* rw    = (const float*)d_in[10];
    const float* resb  = (const float*)d_in[11];
    float* out = (float*)d_out;

    hipLaunchKernelGGL(k_prep, dim3(642), dim3(64), 0, stream,
                       style, dw, rw, s2dw, s2db, qcnn, meas, outw, outb, resb);
    hipLaunchKernelGGL(k_main, dim3(512), dim3(512), 0, stream, x, dpb, out);
}

// Round 6
// 878.122 us; speedup vs baseline: 3.2591x; 3.2591x over previous
//
#include <hip/hip_runtime.h>
#include <math.h>

#define PI_F 3.14159265358979323846f

// Persistent device scratch (rewritten fully on every launch).
__device__ float g_rwT[576 * 64];  // res_proj_w transposed: [p][c]
__device__ float g_dwT[576 * 6];   // data_proj_w transposed: [p][q]
__device__ float g_Ur[64 * 64];    // fixed-circuit unitary, real part [t][s]
__device__ float g_Ui[64 * 64];    // imag part [t][s]
__device__ float g_Zw[64 * 64];    // Zw[t][c] = sum_q out_proj_w[c,q]*sign_q(t)
__device__ float g_sang[48];       // style angles [b][q] (tanh*pi applied)
__device__ float g_cb[64];         // out_proj_b + res_proj_b

// ---------------------------------------------------------------------------
// Prep, 64-thread blocks (unchanged from R5 — proven).
//   bid 0      : Zw + combined bias
//   bid 1      : style angles
//   bid 2..65  : circuit column s = bid-2 (wave butterfly via __shfl_xor)
//   bid 66..641: weight transposes
__global__ __launch_bounds__(64) void k_prep(
        const float* __restrict__ style,
        const float* __restrict__ dw, const float* __restrict__ rw,
        const float* __restrict__ s2dw, const float* __restrict__ s2db,
        const float* __restrict__ qcnn, const float* __restrict__ meas,
        const float* __restrict__ outw, const float* __restrict__ outb,
        const float* __restrict__ resb) {
    int bid = blockIdx.x;
    int t = threadIdx.x;

    if (bid >= 66) {  // transposes
        int i = (bid - 66) * 64 + t;  // 0..36863
        if (i < 576 * 6) { int q = i / 576, p = i % 576; g_dwT[p * 6 + q] = dw[i]; }
        { int c = i / 576, p = i % 576; g_rwT[p * 64 + c] = rw[i]; }
        return;
    }
    if (bid == 0) {  // Zw row t + combined bias
        float zr[6];
#pragma unroll
        for (int q = 0; q < 6; ++q) zr[q] = ((t >> (5 - q)) & 1) ? -1.f : 1.f;
#pragma unroll 8
        for (int c = 0; c < 64; ++c) {
            float z = 0.f;
#pragma unroll
            for (int q = 0; q < 6; ++q) z += outw[c * 6 + q] * zr[q];
            g_Zw[t * 64 + c] = z;
        }
        g_cb[t] = outb[t] + resb[t];
        return;
    }
    if (bid == 1) {  // style angles [b][q]
        if (t < 48) {
            int bb = t / 6, q = t % 6;
            float a = s2db[q];
#pragma unroll 8
            for (int j = 0; j < 128; ++j) a += style[bb * 128 + j] * s2dw[q * 128 + j];
            g_sang[t] = tanhf(a) * PI_F;
        }
        return;
    }

    // Circuit column s: lane t holds amplitude of basis state t (wire q = bit 5-q).
    int s = bid - 2;
    float ar = (t == s) ? 1.f : 0.f;
    float ai = 0.f;

#pragma unroll
    for (int l = 0; l < 2; ++l) {
#pragma unroll
        for (int wq = 0; wq < 6; ++wq) {
            int mask = 1 << (5 - wq);
            bool hi = (t & mask) != 0;
            float th = qcnn[((l * 6 + wq) * 2 + 0) * 3];
            float sg, cg; sincosf(0.5f * th, &sg, &cg);
            float pr = __shfl_xor(ar, mask);
            float pi2 = __shfl_xor(ai, mask);
            ar = hi ? (sg * pr + cg * ar) : (cg * ar - sg * pr);
            ai = hi ? (sg * pi2 + cg * ai) : (cg * ai - sg * pi2);
            float ph = qcnn[((l * 6 + wq) * 2 + 1) * 3];
            float sz, cz; sincosf(0.5f * ph, &sz, &cz);
            float szz = hi ? sz : -sz;
            float nr = cz * ar - szz * ai;
            float ni = cz * ai + szz * ar;
            ar = nr; ai = ni;
        }
#pragma unroll
        for (int wq = 0; wq < 6; ++wq) {  // ring CNOTs
            int cm = 1 << (5 - wq);
            int tm = 1 << (5 - ((wq + 1) % 6));
            float pr = __shfl_xor(ar, tm);
            float pi2 = __shfl_xor(ai, tm);
            if (t & cm) { ar = pr; ai = pi2; }
        }
    }
#pragma unroll
    for (int wq = 0; wq < 6; ++wq) {  // U3 measurement basis
        int mask = 1 << (5 - wq);
        bool hi = (t & mask) != 0;
        float th = meas[wq * 3 + 0], ph = meas[wq * 3 + 1], lm = meas[wq * 3 + 2];
        float st2, ct; sincosf(0.5f * th, &st2, &ct);
        float sl, cl;  sincosf(lm, &sl, &cl);
        float sp, cp;  sincosf(ph, &sp, &cp);
        float spl, cpl; sincosf(ph + lm, &spl, &cpl);
        float u01r = -cl * st2, u01i = -sl * st2;
        float u10r =  cp * st2, u10i =  sp * st2;
        float u11r =  cpl * ct, u11i =  spl * ct;
        float pr = __shfl_xor(ar, mask);
        float pi2 = __shfl_xor(ai, mask);
        float nr, ni;
        if (hi) {
            nr = u10r * pr - u10i * pi2 + u11r * ar - u11i * ai;
            ni = u10r * pi2 + u10i * pr + u11r * ai + u11i * ar;
        } else {
            nr = ct * ar + u01r * pr - u01i * pi2;
            ni = ct * ai + u01r * pi2 + u01i * pr;
        }
        ar = nr; ai = ni;
    }
    g_Ur[t * 64 + s] = ar;
    g_Ui[t * 64 + s] = ai;
}

// ---------------------------------------------------------------------------
// Main (R3 structure, no LDS staging of x): 64 pixels per block, 8 slices.
// Slice owns OUTPUT channels/states [8*slice, 8*slice+8). Conv loads batched
// 8 at a time into v[8] (8 loads in flight -> latency hidden by ILP); angle
// pass fused into the conv (slice's own channel group only).
__global__ __launch_bounds__(512, 4) void k_main(const float* __restrict__ x,
                                                 const float* __restrict__ dpb,
                                                 float* __restrict__ out) {
    __shared__ float lds_ang[6 * 512];   // [q][thread]
    __shared__ float lds_psi[64 * 65];   // [pixel][s]
    __shared__ float lds_prob[64 * 65];  // [pixel][t]

    int lane  = threadIdx.x & 63;
    int slice = __builtin_amdgcn_readfirstlane(threadIdx.x >> 6);  // 0..7
    int c0 = slice * 8;

    int p = blockIdx.x * 64 + lane;      // pixel id: b*4096 + h*64 + w (w==lane)
    int b = p >> 12;
    int h = (p >> 6) & 63;
    const float* xb = x + (b << 18);

    float acc[8];
#pragma unroll
    for (int k = 0; k < 8; ++k) acc[k] = 0.f;
    float ang[6] = {0.f, 0.f, 0.f, 0.f, 0.f, 0.f};

    // ---- fused conv + angle pass. Per (i,j): 8 channel-groups of 8 batched
    // independent loads, then 64 FMAs.
#pragma unroll
    for (int i = 0; i < 3; ++i) {
        int hh = h + i - 1;
        bool hok = (unsigned)hh < 64u;
#pragma unroll
        for (int j = 0; j < 2; ++j) { }  // (placeholder removed below)
#pragma unroll
        for (int j = 0; j < 3; ++j) {
            int ww = lane + j - 1;
            bool ok = hok && (unsigned)ww < 64u;
            const float* xij = xb + (hh << 6) + ww;
#pragma unroll
            for (int cg = 0; cg < 8; ++cg) {
                float v[8];
#pragma unroll
                for (int k = 0; k < 8; ++k) {
                    v[k] = 0.f;
                    if (ok) v[k] = xij[(cg * 8 + k) << 12];
                }
#pragma unroll
                for (int k = 0; k < 8; ++k) {
                    int c = cg * 8 + k;
                    const float* wp = g_rwT + ((c * 9 + i * 3 + j) << 6) + c0;
                    const float4 w0 = *(const float4*)(wp);
                    const float4 w1 = *(const float4*)(wp + 4);
                    acc[0] += v[k] * w0.x; acc[1] += v[k] * w0.y;
                    acc[2] += v[k] * w0.z; acc[3] += v[k] * w0.w;
                    acc[4] += v[k] * w1.x; acc[5] += v[k] * w1.y;
                    acc[6] += v[k] * w1.z; acc[7] += v[k] * w1.w;
                }
                if (cg == slice) {  // this slice's angle channels (c>>3 == cg)
#pragma unroll
                    for (int k = 0; k < 8; ++k) {
                        const float* dp = g_dwT + ((cg * 8 + k) * 9 + i * 3 + j) * 6;
#pragma unroll
                        for (int q = 0; q < 6; ++q) ang[q] += v[k] * dp[q];
                    }
                }
            }
        }
    }
#pragma unroll
    for (int q = 0; q < 6; ++q) lds_ang[q * 512 + threadIdx.x] = ang[q];

    // ---- reduce angles across the 8 slices, finish theta, sincos
    __syncthreads();
    float sc[6], cc[6];
#pragma unroll
    for (int q = 0; q < 6; ++q) {
        const float* a = lds_ang + q * 512 + lane;
        float t = 0.f;
#pragma unroll
        for (int s2 = 0; s2 < 8; ++s2) t += a[s2 * 64];
        float theta = tanhf(t + dpb[q]) * PI_F + g_sang[b * 6 + q];
        sincosf(0.5f * theta, &sc[q], &cc[q]);
    }

    // ---- cooperative psi: this thread builds states s = c0..c0+7
#pragma unroll
    for (int ti = 0; ti < 8; ++ti) {
        int s = c0 + ti;
        float v = ((s >> 5) & 1) ? sc[0] : cc[0];
        v *= ((s >> 4) & 1) ? sc[1] : cc[1];
        v *= ((s >> 3) & 1) ? sc[2] : cc[2];
        v *= ((s >> 2) & 1) ? sc[3] : cc[3];
        v *= ((s >> 1) & 1) ? sc[4] : cc[4];
        v *= (s & 1)        ? sc[5] : cc[5];
        lds_psi[lane * 65 + s] = v;
    }
    __syncthreads();

    // ---- probs for this slice's 8 states: stream psi from LDS in blocks of 8
    float yr[8], yi[8];
#pragma unroll
    for (int t = 0; t < 8; ++t) { yr[t] = 0.f; yi[t] = 0.f; }
#pragma unroll
    for (int s0 = 0; s0 < 8; ++s0) {
        float ps[8];
#pragma unroll
        for (int k = 0; k < 8; ++k) ps[k] = lds_psi[lane * 65 + s0 * 8 + k];
#pragma unroll
        for (int t = 0; t < 8; ++t) {
            const float4 u0 = *(const float4*)(g_Ur + ((c0 + t) << 6) + s0 * 8);
            const float4 u1 = *(const float4*)(g_Ur + ((c0 + t) << 6) + s0 * 8 + 4);
            const float4 v0 = *(const float4*)(g_Ui + ((c0 + t) << 6) + s0 * 8);
            const float4 v1 = *(const float4*)(g_Ui + ((c0 + t) << 6) + s0 * 8 + 4);
            yr[t] += u0.x * ps[0] + u0.y * ps[1] + u0.z * ps[2] + u0.w * ps[3]
                   + u1.x * ps[4] + u1.y * ps[5] + u1.z * ps[6] + u1.w * ps[7];
            yi[t] += v0.x * ps[0] + v0.y * ps[1] + v0.z * ps[2] + v0.w * ps[3]
                   + v1.x * ps[4] + v1.y * ps[5] + v1.z * ps[6] + v1.w * ps[7];
        }
    }
#pragma unroll
    for (int t = 0; t < 8; ++t)
        lds_prob[lane * 65 + c0 + t] = yr[t] * yr[t] + yi[t] * yi[t];
    __syncthreads();

    // ---- fold probs through Zw into this slice's 8 output channels
#pragma unroll 8
    for (int t = 0; t < 64; ++t) {
        float pr = lds_prob[lane * 65 + t];
        const float4 z0 = *(const float4*)(g_Zw + (t << 6) + c0);
        const float4 z1 = *(const float4*)(g_Zw + (t << 6) + c0 + 4);
        acc[0] += pr * z0.x; acc[1] += pr * z0.y;
        acc[2] += pr * z0.z; acc[3] += pr * z0.w;
        acc[4] += pr * z1.x; acc[5] += pr * z1.y;
        acc[6] += pr * z1.z; acc[7] += pr * z1.w;
    }

    // ---- coalesced store: out[b][c][h][w]
    int ob = (b << 18) + (h << 6) + lane;
#pragma unroll
    for (int k = 0; k < 8; ++k) {
        out[ob + ((c0 + k) << 12)] = acc[k] + g_cb[c0 + k];
    }
}

// ---------------------------------------------------------------------------
extern "C" void kernel_launch(void* const* d_in, const int* in_sizes, int n_in,
                              void* d_out, int out_size, void* d_ws, size_t ws_size,
                              hipStream_t stream) {
    const float* x     = (const float*)d_in[0];
    const float* style = (const float*)d_in[1];
    const float* dw    = (const float*)d_in[2];
    const float* dpb   = (const float*)d_in[3];
    const float* s2dw  = (const float*)d_in[4];
    const float* s2db  = (const float*)d_in[5];
    const float* qcnn  = (const float*)d_in[6];
    const float* meas  = (const float*)d_in[7];
    const float* outw  = (const float*)d_in[8];
    const float* outb  = (const float*)d_in[9];
    const float* rw    = (const float*)d_in[10];
    const float* resb  = (const float*)d_in[11];
    float* out = (float*)d_out;

    hipLaunchKernelGGL(k_prep, dim3(642), dim3(64), 0, stream,
                       style, dw, rw, s2dw, s2db, qcnn, meas, outw, outb, resb);
    hipLaunchKernelGGL(k_main, dim3(512), dim3(512), 0, stream, x, dpb, out);
}

// Round 7
// 313.825 us; speedup vs baseline: 9.1193x; 2.7981x over previous
//
#include <hip/hip_runtime.h>
#include <math.h>

#define PI_F 3.14159265358979323846f

// Persistent device scratch (rewritten fully on every launch).
__device__ float g_rwT[576 * 64];  // res_proj_w transposed: [p][c]
__device__ float g_dwT[576 * 6];   // data_proj_w transposed: [p][q]
__device__ float g_Ur[64 * 64];    // fixed-circuit unitary, real part [t][s]
__device__ float g_Ui[64 * 64];    // imag part [t][s]
__device__ float g_Zw[64 * 64];    // Zw[t][c] = sum_q out_proj_w[c,q]*sign_q(t)
__device__ float g_sang[48];       // style angles [b][q] (tanh*pi applied)
__device__ float g_cb[64];         // out_proj_b + res_proj_b

// ---------------------------------------------------------------------------
// Prep, 64-thread blocks (unchanged from R5/R6 — proven fast).
//   bid 0      : Zw + combined bias
//   bid 1      : style angles
//   bid 2..65  : circuit column s = bid-2 (wave butterfly via __shfl_xor)
//   bid 66..641: weight transposes
__global__ __launch_bounds__(64) void k_prep(
        const float* __restrict__ style,
        const float* __restrict__ dw, const float* __restrict__ rw,
        const float* __restrict__ s2dw, const float* __restrict__ s2db,
        const float* __restrict__ qcnn, const float* __restrict__ meas,
        const float* __restrict__ outw, const float* __restrict__ outb,
        const float* __restrict__ resb) {
    int bid = blockIdx.x;
    int t = threadIdx.x;

    if (bid >= 66) {  // transposes
        int i = (bid - 66) * 64 + t;  // 0..36863
        if (i < 576 * 6) { int q = i / 576, p = i % 576; g_dwT[p * 6 + q] = dw[i]; }
        { int c = i / 576, p = i % 576; g_rwT[p * 64 + c] = rw[i]; }
        return;
    }
    if (bid == 0) {  // Zw row t + combined bias
        float zr[6];
#pragma unroll
        for (int q = 0; q < 6; ++q) zr[q] = ((t >> (5 - q)) & 1) ? -1.f : 1.f;
#pragma unroll 8
        for (int c = 0; c < 64; ++c) {
            float z = 0.f;
#pragma unroll
            for (int q = 0; q < 6; ++q) z += outw[c * 6 + q] * zr[q];
            g_Zw[t * 64 + c] = z;
        }
        g_cb[t] = outb[t] + resb[t];
        return;
    }
    if (bid == 1) {  // style angles [b][q]
        if (t < 48) {
            int bb = t / 6, q = t % 6;
            float a = s2db[q];
#pragma unroll 8
            for (int j = 0; j < 128; ++j) a += style[bb * 128 + j] * s2dw[q * 128 + j];
            g_sang[t] = tanhf(a) * PI_F;
        }
        return;
    }

    // Circuit column s: lane t holds amplitude of basis state t (wire q = bit 5-q).
    int s = bid - 2;
    float ar = (t == s) ? 1.f : 0.f;
    float ai = 0.f;

#pragma unroll
    for (int l = 0; l < 2; ++l) {
#pragma unroll
        for (int wq = 0; wq < 6; ++wq) {
            int mask = 1 << (5 - wq);
            bool hi = (t & mask) != 0;
            float th = qcnn[((l * 6 + wq) * 2 + 0) * 3];
            float sg, cg; sincosf(0.5f * th, &sg, &cg);
            float pr = __shfl_xor(ar, mask);
            float pi2 = __shfl_xor(ai, mask);
            ar = hi ? (sg * pr + cg * ar) : (cg * ar - sg * pr);
            ai = hi ? (sg * pi2 + cg * ai) : (cg * ai - sg * pi2);
            float ph = qcnn[((l * 6 + wq) * 2 + 1) * 3];
            float sz, cz; sincosf(0.5f * ph, &sz, &cz);
            float szz = hi ? sz : -sz;
            float nr = cz * ar - szz * ai;
            float ni = cz * ai + szz * ar;
            ar = nr; ai = ni;
        }
#pragma unroll
        for (int wq = 0; wq < 6; ++wq) {  // ring CNOTs
            int cm = 1 << (5 - wq);
            int tm = 1 << (5 - ((wq + 1) % 6));
            float pr = __shfl_xor(ar, tm);
            float pi2 = __shfl_xor(ai, tm);
            if (t & cm) { ar = pr; ai = pi2; }
        }
    }
#pragma unroll
    for (int wq = 0; wq < 6; ++wq) {  // U3 measurement basis
        int mask = 1 << (5 - wq);
        bool hi = (t & mask) != 0;
        float th = meas[wq * 3 + 0], ph = meas[wq * 3 + 1], lm = meas[wq * 3 + 2];
        float st2, ct; sincosf(0.5f * th, &st2, &ct);
        float sl, cl;  sincosf(lm, &sl, &cl);
        float sp, cp;  sincosf(ph, &sp, &cp);
        float spl, cpl; sincosf(ph + lm, &spl, &cpl);
        float u01r = -cl * st2, u01i = -sl * st2;
        float u10r =  cp * st2, u10i =  sp * st2;
        float u11r =  cpl * ct, u11i =  spl * ct;
        float pr = __shfl_xor(ar, mask);
        float pi2 = __shfl_xor(ai, mask);
        float nr, ni;
        if (hi) {
            nr = u10r * pr - u10i * pi2 + u11r * ar - u11i * ai;
            ni = u10r * pi2 + u10i * pr + u11r * ai + u11i * ar;
        } else {
            nr = ct * ar + u01r * pr - u01i * pi2;
            ni = ct * ai + u01r * pi2 + u01i * pr;
        }
        ar = nr; ai = ni;
    }
    g_Ur[t * 64 + s] = ar;
    g_Ui[t * 64 + s] = ai;
}

// ---------------------------------------------------------------------------
// Main, K-split x2 for occupancy: 32 pixels x 16 groups = 512 threads/block,
// grid 1024 (2x the waves of R3 at same per-CU LDS/VGPR budget).
// group = (khalf, slice): khalf = grp>>3 (wave-uniform), slice = grp&7.
// Conv: channels [khalf*32, +32) -> outputs [slice*8, +8)   (R3 loop body!)
// Angles: channels [grp*4, +4). Quantum: psi states [grp*4,+4), U rows
// [grp*4,+4). khalf=1's acc merged into khalf=0 via LDS; khalf=0 stores.
__global__ __launch_bounds__(512, 4) void k_main(const float* __restrict__ x,
                                                 const float* __restrict__ dpb,
                                                 float* __restrict__ out) {
    __shared__ float lds_ang[6 * 512];   // [q][tid]             12 KB
    __shared__ float lds_acc[32 * 65];   // [pix][c] khalf1 half  8.3 KB
    __shared__ float lds_psi[32 * 65];   // [pix][s]              8.3 KB
    __shared__ float lds_prob[32 * 65];  // [pix][t]              8.3 KB

    int tid   = threadIdx.x;
    int pix   = tid & 31;
    int grp   = tid >> 5;        // 0..15
    int slice = grp & 7;
    int khalf = grp >> 3;        // wave-uniform (waves 0-3: 0, waves 4-7: 1)
    int c0 = slice * 8;

    int p = blockIdx.x * 32 + pix;   // pixel id: b*4096 + h*64 + w
    int b = p >> 12;
    int h = (p >> 6) & 63;
    int w = p & 63;
    const float* xb = x + (b << 18);

    // ---- pass 1: data-angle partials over this group's 4 channels
    float ang[6] = {0.f, 0.f, 0.f, 0.f, 0.f, 0.f};
    for (int ci = 0; ci < 4; ++ci) {
        int c = grp * 4 + ci;
        const float* xc = xb + (c << 12);
#pragma unroll
        for (int i = 0; i < 3; ++i) {
            int hh = h + i - 1;
            bool hok = (unsigned)hh < 64u;
#pragma unroll
            for (int j = 0; j < 3; ++j) {
                int ww = w + j - 1;
                float v = 0.f;
                if (hok && (unsigned)ww < 64u) v = xc[(hh << 6) + ww];
                const float* dwp = g_dwT + (c * 9 + i * 3 + j) * 6;
#pragma unroll
                for (int q = 0; q < 6; ++q) ang[q] += v * dwp[q];
            }
        }
    }
#pragma unroll
    for (int q = 0; q < 6; ++q) lds_ang[q * 512 + tid] = ang[q];

    // ---- pass 2: res conv over this khalf's 32 channels (R3-proven body)
    float acc[8];
#pragma unroll
    for (int k = 0; k < 8; ++k) acc[k] = 0.f;
    int cb = khalf * 32;
#pragma unroll
    for (int i = 0; i < 3; ++i) {
        int hh = h + i - 1;
        bool hok = (unsigned)hh < 64u;
#pragma unroll
        for (int j = 0; j < 3; ++j) {
            int ww = w + j - 1;
            bool ok = hok && (unsigned)ww < 64u;
            const float* xij = xb + (hh << 6) + ww + (cb << 12);
            const float* wij = g_rwT + ((i * 3 + j) << 6) + ((cb * 9) << 6) + c0;
#pragma unroll 4
            for (int c = 0; c < 32; ++c) {
                float v = 0.f;
                if (ok) v = xij[c << 12];
                const float4 w0 = *(const float4*)(wij + c * 576);
                const float4 w1 = *(const float4*)(wij + c * 576 + 4);
                acc[0] += v * w0.x; acc[1] += v * w0.y;
                acc[2] += v * w0.z; acc[3] += v * w0.w;
                acc[4] += v * w1.x; acc[5] += v * w1.y;
                acc[6] += v * w1.z; acc[7] += v * w1.w;
            }
        }
    }
    // khalf=1 parks its partial acc in LDS (khalf uniform per wave)
    if (khalf) {
#pragma unroll
        for (int k = 0; k < 8; ++k) lds_acc[pix * 65 + c0 + k] = acc[k];
    }
    __syncthreads();
    if (!khalf) {
#pragma unroll
        for (int k = 0; k < 8; ++k) acc[k] += lds_acc[pix * 65 + c0 + k];
    }

    // ---- reduce angles across the 16 groups, finish theta, sincos
    float sc[6], cc[6];
#pragma unroll
    for (int q = 0; q < 6; ++q) {
        const float* a = lds_ang + q * 512 + pix;
        float t = 0.f;
#pragma unroll
        for (int g2 = 0; g2 < 16; ++g2) t += a[g2 * 32];
        float theta = tanhf(t + dpb[q]) * PI_F + g_sang[b * 6 + q];
        sincosf(0.5f * theta, &sc[q], &cc[q]);
    }

    // ---- cooperative psi: this group builds states s = grp*4 .. grp*4+3
#pragma unroll
    for (int ti = 0; ti < 4; ++ti) {
        int s = grp * 4 + ti;
        float v = ((s >> 5) & 1) ? sc[0] : cc[0];
        v *= ((s >> 4) & 1) ? sc[1] : cc[1];
        v *= ((s >> 3) & 1) ? sc[2] : cc[2];
        v *= ((s >> 2) & 1) ? sc[3] : cc[3];
        v *= ((s >> 1) & 1) ? sc[4] : cc[4];
        v *= (s & 1)        ? sc[5] : cc[5];
        lds_psi[pix * 65 + s] = v;
    }
    __syncthreads();

    // ---- probs for this group's 4 states: stream psi from LDS in blocks of 8
    int t0 = grp * 4;
    float yr[4], yi[4];
#pragma unroll
    for (int t = 0; t < 4; ++t) { yr[t] = 0.f; yi[t] = 0.f; }
#pragma unroll
    for (int s0 = 0; s0 < 8; ++s0) {
        float ps[8];
#pragma unroll
        for (int k = 0; k < 8; ++k) ps[k] = lds_psi[pix * 65 + s0 * 8 + k];
#pragma unroll
        for (int t = 0; t < 4; ++t) {
            const float4 u0 = *(const float4*)(g_Ur + ((t0 + t) << 6) + s0 * 8);
            const float4 u1 = *(const float4*)(g_Ur + ((t0 + t) << 6) + s0 * 8 + 4);
            const float4 v0 = *(const float4*)(g_Ui + ((t0 + t) << 6) + s0 * 8);
            const float4 v1 = *(const float4*)(g_Ui + ((t0 + t) << 6) + s0 * 8 + 4);
            yr[t] += u0.x * ps[0] + u0.y * ps[1] + u0.z * ps[2] + u0.w * ps[3]
                   + u1.x * ps[4] + u1.y * ps[5] + u1.z * ps[6] + u1.w * ps[7];
            yi[t] += v0.x * ps[0] + v0.y * ps[1] + v0.z * ps[2] + v0.w * ps[3]
                   + v1.x * ps[4] + v1.y * ps[5] + v1.z * ps[6] + v1.w * ps[7];
        }
    }
#pragma unroll
    for (int t = 0; t < 4; ++t)
        lds_prob[pix * 65 + t0 + t] = yr[t] * yr[t] + yi[t] * yi[t];
    __syncthreads();

    // ---- khalf=0 folds probs through Zw into its 8 output channels + stores
    if (!khalf) {
#pragma unroll 8
        for (int t = 0; t < 64; ++t) {
            float pr = lds_prob[pix * 65 + t];
            const float4 z0 = *(const float4*)(g_Zw + (t << 6) + c0);
            const float4 z1 = *(const float4*)(g_Zw + (t << 6) + c0 + 4);
            acc[0] += pr * z0.x; acc[1] += pr * z0.y;
            acc[2] += pr * z0.z; acc[3] += pr * z0.w;
            acc[4] += pr * z1.x; acc[5] += pr * z1.y;
            acc[6] += pr * z1.z; acc[7] += pr * z1.w;
        }
        int ob = (b << 18) + (h << 6) + w;
#pragma unroll
        for (int k = 0; k < 8; ++k) {
            out[ob + ((c0 + k) << 12)] = acc[k] + g_cb[c0 + k];
        }
    }
}

// ---------------------------------------------------------------------------
extern "C" void kernel_launch(void* const* d_in, const int* in_sizes, int n_in,
                              void* d_out, int out_size, void* d_ws, size_t ws_size,
                              hipStream_t stream) {
    const float* x     = (const float*)d_in[0];
    const float* style = (const float*)d_in[1];
    const float* dw    = (const float*)d_in[2];
    const float* dpb   = (const float*)d_in[3];
    const float* s2dw  = (const float*)d_in[4];
    const float* s2db  = (const float*)d_in[5];
    const float* qcnn  = (const float*)d_in[6];
    const float* meas  = (const float*)d_in[7];
    const float* outw  = (const float*)d_in[8];
    const float* outb  = (const float*)d_in[9];
    const float* rw    = (const float*)d_in[10];
    const float* resb  = (const float*)d_in[11];
    float* out = (float*)d_out;

    hipLaunchKernelGGL(k_prep, dim3(642), dim3(64), 0, stream,
                       style, dw, rw, s2dw, s2db, qcnn, meas, outw, outb, resb);
    hipLaunchKernelGGL(k_main, dim3(1024), dim3(512), 0, stream, x, dpb, out);
}

// Round 8
// 181.740 us; speedup vs baseline: 15.7471x; 1.7268x over previous
//
#include <hip/hip_runtime.h>
#include <math.h>

#define PI_F 3.14159265358979323846f

// Persistent device scratch (rewritten fully on every launch).
__device__ float g_rwT[576 * 64];  // res_proj_w transposed: [p][c]
__device__ float g_dwT[576 * 6];   // data_proj_w transposed: [p][q]
__device__ float g_Ur[64 * 64];    // fixed-circuit unitary, real part [t][s]
__device__ float g_Ui[64 * 64];    // imag part [t][s]
__device__ float g_Zw[64 * 64];    // Zw[t][c] = sum_q out_proj_w[c,q]*sign_q(t)
__device__ float g_sang[48];       // style angles [b][q] (tanh*pi applied)
__device__ float g_cb[64];         // out_proj_b + res_proj_b

// ---------------------------------------------------------------------------
// Prep, 64-thread blocks (unchanged from R5-R7 — proven fast).
//   bid 0      : Zw + combined bias
//   bid 1      : style angles
//   bid 2..65  : circuit column s = bid-2 (wave butterfly via __shfl_xor)
//   bid 66..641: weight transposes
__global__ __launch_bounds__(64) void k_prep(
        const float* __restrict__ style,
        const float* __restrict__ dw, const float* __restrict__ rw,
        const float* __restrict__ s2dw, const float* __restrict__ s2db,
        const float* __restrict__ qcnn, const float* __restrict__ meas,
        const float* __restrict__ outw, const float* __restrict__ outb,
        const float* __restrict__ resb) {
    int bid = blockIdx.x;
    int t = threadIdx.x;

    if (bid >= 66) {  // transposes
        int i = (bid - 66) * 64 + t;  // 0..36863
        if (i < 576 * 6) { int q = i / 576, p = i % 576; g_dwT[p * 6 + q] = dw[i]; }
        { int c = i / 576, p = i % 576; g_rwT[p * 64 + c] = rw[i]; }
        return;
    }
    if (bid == 0) {  // Zw row t + combined bias
        float zr[6];
#pragma unroll
        for (int q = 0; q < 6; ++q) zr[q] = ((t >> (5 - q)) & 1) ? -1.f : 1.f;
#pragma unroll 8
        for (int c = 0; c < 64; ++c) {
            float z = 0.f;
#pragma unroll
            for (int q = 0; q < 6; ++q) z += outw[c * 6 + q] * zr[q];
            g_Zw[t * 64 + c] = z;
        }
        g_cb[t] = outb[t] + resb[t];
        return;
    }
    if (bid == 1) {  // style angles [b][q]
        if (t < 48) {
            int bb = t / 6, q = t % 6;
            float a = s2db[q];
#pragma unroll 8
            for (int j = 0; j < 128; ++j) a += style[bb * 128 + j] * s2dw[q * 128 + j];
            g_sang[t] = tanhf(a) * PI_F;
        }
        return;
    }

    // Circuit column s: lane t holds amplitude of basis state t (wire q = bit 5-q).
    int s = bid - 2;
    float ar = (t == s) ? 1.f : 0.f;
    float ai = 0.f;

#pragma unroll
    for (int l = 0; l < 2; ++l) {
#pragma unroll
        for (int wq = 0; wq < 6; ++wq) {
            int mask = 1 << (5 - wq);
            bool hi = (t & mask) != 0;
            float th = qcnn[((l * 6 + wq) * 2 + 0) * 3];
            float sg, cg; sincosf(0.5f * th, &sg, &cg);
            float pr = __shfl_xor(ar, mask);
            float pi2 = __shfl_xor(ai, mask);
            ar = hi ? (sg * pr + cg * ar) : (cg * ar - sg * pr);
            ai = hi ? (sg * pi2 + cg * ai) : (cg * ai - sg * pi2);
            float ph = qcnn[((l * 6 + wq) * 2 + 1) * 3];
            float sz, cz; sincosf(0.5f * ph, &sz, &cz);
            float szz = hi ? sz : -sz;
            float nr = cz * ar - szz * ai;
            float ni = cz * ai + szz * ar;
            ar = nr; ai = ni;
        }
#pragma unroll
        for (int wq = 0; wq < 6; ++wq) {  // ring CNOTs
            int cm = 1 << (5 - wq);
            int tm = 1 << (5 - ((wq + 1) % 6));
            float pr = __shfl_xor(ar, tm);
            float pi2 = __shfl_xor(ai, tm);
            if (t & cm) { ar = pr; ai = pi2; }
        }
    }
#pragma unroll
    for (int wq = 0; wq < 6; ++wq) {  // U3 measurement basis
        int mask = 1 << (5 - wq);
        bool hi = (t & mask) != 0;
        float th = meas[wq * 3 + 0], ph = meas[wq * 3 + 1], lm = meas[wq * 3 + 2];
        float st2, ct; sincosf(0.5f * th, &st2, &ct);
        float sl, cl;  sincosf(lm, &sl, &cl);
        float sp, cp;  sincosf(ph, &sp, &cp);
        float spl, cpl; sincosf(ph + lm, &spl, &cpl);
        float u01r = -cl * st2, u01i = -sl * st2;
        float u10r =  cp * st2, u10i =  sp * st2;
        float u11r =  cpl * ct, u11i =  spl * ct;
        float pr = __shfl_xor(ar, mask);
        float pi2 = __shfl_xor(ai, mask);
        float nr, ni;
        if (hi) {
            nr = u10r * pr - u10i * pi2 + u11r * ar - u11i * ai;
            ni = u10r * pi2 + u10i * pr + u11r * ai + u11i * ar;
        } else {
            nr = ct * ar + u01r * pr - u01i * pi2;
            ni = ct * ai + u01r * pi2 + u01i * pr;
        }
        ar = nr; ai = ni;
    }
    g_Ur[t * 64 + s] = ar;
    g_Ui[t * 64 + s] = ai;
}

// ---------------------------------------------------------------------------
// Main, K-split x2 with wave-uniform groups: 1024 threads = 64 pixels (lane)
// x 16 waves. wave wid: slice = wid&7 (owns output chans/states [8s,8s+8)),
// khalf = wid>>3 (owns input chans [32k,32k+32)). Both readfirstlane'd ->
// all weight/U/Zw addresses stay scalar (s_load), exactly like R3.
// Grid 512 -> 2 blocks/CU -> 32 waves/CU (2x R3) if VGPR<=64 (R3 body = 64).
__global__ __launch_bounds__(1024, 4) void k_main(const float* __restrict__ x,
                                                  const float* __restrict__ dpb,
                                                  float* __restrict__ out) {
    __shared__ float lds_ang[6 * 1024];  // [q][tid]                 24.6 KB
    __shared__ float lds_acc[64 * 65];   // [pix][c] khalf1 partial  16.6 KB
    __shared__ float lds_psi[64 * 65];   // [pix][s]                 16.6 KB
    __shared__ float lds_prob[64 * 65];  // [pix][t]                 16.6 KB

    int tid  = threadIdx.x;
    int lane = tid & 63;                 // pixel within block (== w)
    int wid  = __builtin_amdgcn_readfirstlane(tid >> 6);  // 0..15
    int slice = wid & 7;
    int khalf = wid >> 3;
    int c0 = slice * 8;

    int p = blockIdx.x * 64 + lane;      // pixel id: b*4096 + h*64 + w
    int b = p >> 12;
    int h = (p >> 6) & 63;
    int w = p & 63;
    const float* xb = x + (b << 18);

    // ---- pass 1: data-angle partials over this group's 4 channels
    float ang[6] = {0.f, 0.f, 0.f, 0.f, 0.f, 0.f};
    for (int ci = 0; ci < 4; ++ci) {
        int c = wid * 4 + ci;
        const float* xc = xb + (c << 12);
#pragma unroll
        for (int i = 0; i < 3; ++i) {
            int hh = h + i - 1;
            bool hok = (unsigned)hh < 64u;
#pragma unroll
            for (int j = 0; j < 3; ++j) {
                int ww = w + j - 1;
                float v = 0.f;
                if (hok && (unsigned)ww < 64u) v = xc[(hh << 6) + ww];
                const float* dwp = g_dwT + (c * 9 + i * 3 + j) * 6;
#pragma unroll
                for (int q = 0; q < 6; ++q) ang[q] += v * dwp[q];
            }
        }
    }
#pragma unroll
    for (int q = 0; q < 6; ++q) lds_ang[q * 1024 + tid] = ang[q];

    // ---- pass 2: res conv over this khalf's 32 input channels (R3 body)
    float acc[8];
#pragma unroll
    for (int k = 0; k < 8; ++k) acc[k] = 0.f;
    int cb = khalf * 32;
#pragma unroll
    for (int i = 0; i < 3; ++i) {
        int hh = h + i - 1;
        bool hok = (unsigned)hh < 64u;
#pragma unroll
        for (int j = 0; j < 3; ++j) {
            int ww = w + j - 1;
            bool ok = hok && (unsigned)ww < 64u;
            const float* xij = xb + (hh << 6) + ww + (cb << 12);
            const float* wij = g_rwT + ((cb * 9) << 6) + ((i * 3 + j) << 6) + c0;
#pragma unroll 4
            for (int c = 0; c < 32; ++c) {
                float v = 0.f;
                if (ok) v = xij[c << 12];
                const float4 w0 = *(const float4*)(wij + c * 576);
                const float4 w1 = *(const float4*)(wij + c * 576 + 4);
                acc[0] += v * w0.x; acc[1] += v * w0.y;
                acc[2] += v * w0.z; acc[3] += v * w0.w;
                acc[4] += v * w1.x; acc[5] += v * w1.y;
                acc[6] += v * w1.z; acc[7] += v * w1.w;
            }
        }
    }
    // khalf=1 parks its conv partial (wave-uniform branch)
    if (khalf) {
#pragma unroll
        for (int k = 0; k < 8; ++k) lds_acc[lane * 65 + c0 + k] = acc[k];
    }
    __syncthreads();
    if (!khalf) {
#pragma unroll
        for (int k = 0; k < 8; ++k) acc[k] += lds_acc[lane * 65 + c0 + k];
    }

    // ---- reduce angles across the 16 groups, finish theta, sincos
    float sc[6], cc[6];
#pragma unroll
    for (int q = 0; q < 6; ++q) {
        const float* a = lds_ang + q * 1024 + lane;
        float t = 0.f;
#pragma unroll
        for (int g2 = 0; g2 < 16; ++g2) t += a[g2 * 64];
        float theta = tanhf(t + dpb[q]) * PI_F + g_sang[b * 6 + q];
        sincosf(0.5f * theta, &sc[q], &cc[q]);
    }

    // ---- cooperative psi: this group builds states s = wid*4 .. wid*4+3
#pragma unroll
    for (int ti = 0; ti < 4; ++ti) {
        int s = wid * 4 + ti;
        float v = ((s >> 5) & 1) ? sc[0] : cc[0];
        v *= ((s >> 4) & 1) ? sc[1] : cc[1];
        v *= ((s >> 3) & 1) ? sc[2] : cc[2];
        v *= ((s >> 2) & 1) ? sc[3] : cc[3];
        v *= ((s >> 1) & 1) ? sc[4] : cc[4];
        v *= (s & 1)        ? sc[5] : cc[5];
        lds_psi[lane * 65 + s] = v;
    }
    __syncthreads();

    // ---- probs for this group's 4 states: stream psi from LDS in blocks of 8
    int t0 = wid * 4;
    float yr[4], yi[4];
#pragma unroll
    for (int t = 0; t < 4; ++t) { yr[t] = 0.f; yi[t] = 0.f; }
#pragma unroll
    for (int s0 = 0; s0 < 8; ++s0) {
        float ps[8];
#pragma unroll
        for (int k = 0; k < 8; ++k) ps[k] = lds_psi[lane * 65 + s0 * 8 + k];
#pragma unroll
        for (int t = 0; t < 4; ++t) {
            const float4 u0 = *(const float4*)(g_Ur + ((t0 + t) << 6) + s0 * 8);
            const float4 u1 = *(const float4*)(g_Ur + ((t0 + t) << 6) + s0 * 8 + 4);
            const float4 v0 = *(const float4*)(g_Ui + ((t0 + t) << 6) + s0 * 8);
            const float4 v1 = *(const float4*)(g_Ui + ((t0 + t) << 6) + s0 * 8 + 4);
            yr[t] += u0.x * ps[0] + u0.y * ps[1] + u0.z * ps[2] + u0.w * ps[3]
                   + u1.x * ps[4] + u1.y * ps[5] + u1.z * ps[6] + u1.w * ps[7];
            yi[t] += v0.x * ps[0] + v0.y * ps[1] + v0.z * ps[2] + v0.w * ps[3]
                   + v1.x * ps[4] + v1.y * ps[5] + v1.z * ps[6] + v1.w * ps[7];
        }
    }
#pragma unroll
    for (int t = 0; t < 4; ++t)
        lds_prob[lane * 65 + t0 + t] = yr[t] * yr[t] + yi[t] * yi[t];
    __syncthreads();

    // ---- khalf=0 folds probs through Zw into its 8 output channels + stores
    if (!khalf) {
#pragma unroll 8
        for (int t = 0; t < 64; ++t) {
            float pr = lds_prob[lane * 65 + t];
            const float4 z0 = *(const float4*)(g_Zw + (t << 6) + c0);
            const float4 z1 = *(const float4*)(g_Zw + (t << 6) + c0 + 4);
            acc[0] += pr * z0.x; acc[1] += pr * z0.y;
            acc[2] += pr * z0.z; acc[3] += pr * z0.w;
            acc[4] += pr * z1.x; acc[5] += pr * z1.y;
            acc[6] += pr * z1.z; acc[7] += pr * z1.w;
        }
        int ob = (b << 18) + (h << 6) + w;
#pragma unroll
        for (int k = 0; k < 8; ++k) {
            out[ob + ((c0 + k) << 12)] = acc[k] + g_cb[c0 + k];
        }
    }
}

// ---------------------------------------------------------------------------
extern "C" void kernel_launch(void* const* d_in, const int* in_sizes, int n_in,
                              void* d_out, int out_size, void* d_ws, size_t ws_size,
                              hipStream_t stream) {
    const float* x     = (const float*)d_in[0];
    const float* style = (const float*)d_in[1];
    const float* dw    = (const float*)d_in[2];
    const float* dpb   = (const float*)d_in[3];
    const float* s2dw  = (const float*)d_in[4];
    const float* s2db  = (const float*)d_in[5];
    const float* qcnn  = (const float*)d_in[6];
    const float* meas  = (const float*)d_in[7];
    const float* outw  = (const float*)d_in[8];
    const float* outb  = (const float*)d_in[9];
    const float* rw    = (const float*)d_in[10];
    const float* resb  = (const float*)d_in[11];
    float* out = (float*)d_out;

    hipLaunchKernelGGL(k_prep, dim3(642), dim3(64), 0, stream,
                       style, dw, rw, s2dw, s2db, qcnn, meas, outw, outb, resb);
    hipLaunchKernelGGL(k_main, dim3(512), dim3(1024), 0, stream, x, dpb, out);
}